// Round 11
// baseline (179.523 us; speedup 1.0000x reference)
//
#include <hip/hip_runtime.h>
#include <hip/hip_bf16.h>
#include <stdint.h>

#define BS   16384
#define NC   2000
#define NCP  2048            // padded N (wn zero-filled rows 2000..2047)
#define EMB  512
#define NAUX 5
#define NCHUNK 32            // partial chunks per row: nTile*2 + wvN
#define GBLK 2048            // gather_fin blocks (8 rows each)

typedef __bf16 bf16x8 __attribute__((ext_vector_type(8)));
typedef float  f32x4  __attribute__((ext_vector_type(4)));

// ---------------------------------------------------------------------------
// Kernel 1: row-normalize features (rows [0,BS)) and word_embed ([BS,BS+NC))
// into bf16; zero-fill wn padding rows [NC,NCP). 16 lanes per row.
// ---------------------------------------------------------------------------
__global__ __launch_bounds__(256) void norm_kernel(
    const float* __restrict__ feat, const float* __restrict__ wemb,
    __bf16* __restrict__ fn, __bf16* __restrict__ wn)
{
    const int sub = threadIdx.x & 15;                    // lane-in-row
    const int row = blockIdx.x * 16 + (threadIdx.x >> 4);

    if (row >= BS + NC) {  // padding rows of wn -> zeros (masked in epilogue)
        bf16x8 z = {};
        bf16x8* d = (bf16x8*)(wn + (size_t)(row - BS) * EMB) + sub * 4;
        #pragma unroll
        for (int i = 0; i < 4; ++i) d[i] = z;
        return;
    }
    const float* src;
    __bf16* dst;
    if (row < BS) { src = feat + (size_t)row * EMB;        dst = fn + (size_t)row * EMB; }
    else          { src = wemb + (size_t)(row - BS) * EMB; dst = wn + (size_t)(row - BS) * EMB; }

    const float4* s4 = (const float4*)src + sub * 8;     // 32 floats per lane
    float4 x[8];
    float ss = 0.f;
    #pragma unroll
    for (int i = 0; i < 8; ++i) {
        x[i] = s4[i];
        ss += x[i].x * x[i].x + x[i].y * x[i].y + x[i].z * x[i].z + x[i].w * x[i].w;
    }
    #pragma unroll
    for (int m = 1; m < 16; m <<= 1) ss += __shfl_xor(ss, m, 64);
    const float scale = 1.0f / fmaxf(sqrtf(ss), 1e-12f);

    bf16x8* d = (bf16x8*)dst + sub * 4;
    #pragma unroll
    for (int i = 0; i < 4; ++i) {
        bf16x8 o;
        o[0] = (__bf16)(x[2*i].x   * scale); o[1] = (__bf16)(x[2*i].y   * scale);
        o[2] = (__bf16)(x[2*i].z   * scale); o[3] = (__bf16)(x[2*i].w   * scale);
        o[4] = (__bf16)(x[2*i+1].x * scale); o[5] = (__bf16)(x[2*i+1].y * scale);
        o[6] = (__bf16)(x[2*i+1].z * scale); o[7] = (__bf16)(x[2*i+1].w * scale);
        d[i] = o;
    }
}

// ---------------------------------------------------------------------------
// Kernel 2: XCD-swizzled m97 GEMM (reproducibly 66.8 µs; unchanged from r10).
//   128x128 tile, BK=64, 4 waves 2x2, global_load_lds width=16 staging with
//   explicit s_waitcnt(0) before the barrier, 16B-chunk XOR bank swizzle.
//   XCD swizzle: xcd=bid&7 owns 16 mTiles, mTile-major -> A fetched from HBM
//   once chip-wide; wn (2 MB) L2-resident. Partials [row][NCHUNK].
// mfma_f32_16x16x32_bf16 verified layouts:
//   A frag: lane(m=lane&15, q=lane>>4) holds A[m][q*8+j]
//   B frag: lane(n=lane&15, q)         holds B[q*8+j][n] = wn[n][q*8+j]
//   C/D:    col(n) = lane&15, row(m) = q*4 + reg
// ---------------------------------------------------------------------------
__global__ __launch_bounds__(256) void main_kernel(
    const __bf16* __restrict__ fn, const __bf16* __restrict__ wn,
    float* __restrict__ es_p, unsigned* __restrict__ key_p)
{
    __shared__ __align__(16) __bf16 As[128 * 64];
    __shared__ __align__(16) __bf16 Bs[128 * 64];

    const int tid   = threadIdx.x;
    const int lane  = tid & 63;
    const int l15   = lane & 15;
    const int quad  = lane >> 4;
    const int wv    = tid >> 6;
    const int wvM   = wv >> 1;
    const int wvN   = wv & 1;
    const int xcd   = blockIdx.x & 7;
    const int j     = blockIdx.x >> 3;           // 0..255 within XCD
    const int mTile = xcd * 16 + (j >> 4);       // 0..127
    const int nTile = j & 15;                    // 0..15

    const __bf16* fbase = fn + (size_t)mTile * 128 * EMB;
    const __bf16* wbase = wn + (size_t)nTile * 128 * EMB;

    const int sRowIn = lane >> 3;                 // 0..7
    const int sChunk = (lane & 7) ^ sRowIn;       // logical 16B chunk to fetch
    f32x4 acc[4][4] = {};

    for (int kk = 0; kk < EMB; kk += 64) {
        __syncthreads();                          // previous tile's readers done
        #pragma unroll
        for (int p = 0; p < 4; ++p) {
            const int slot = wv * 4 + p;
            const size_t goff = (size_t)(slot * 8 + sRowIn) * EMB + kk + sChunk * 8;
            __builtin_amdgcn_global_load_lds(
                (const __attribute__((address_space(1))) void*)(fbase + goff),
                (__attribute__((address_space(3))) void*)(As + slot * 512), 16, 0, 0);
            __builtin_amdgcn_global_load_lds(
                (const __attribute__((address_space(1))) void*)(wbase + goff),
                (__attribute__((address_space(3))) void*)(Bs + slot * 512), 16, 0, 0);
        }
        __builtin_amdgcn_s_waitcnt(0);            // drain global->LDS DMA
        __syncthreads();                          // staged tile visible to all

        #pragma unroll
        for (int kc = 0; kc < 2; ++kc) {
            bf16x8 aF[4], bF[4];
            #pragma unroll
            for (int i = 0; i < 4; ++i) {
                const int ar = wvM * 64 + i * 16 + l15;
                const int br = wvN * 64 + i * 16 + l15;
                const int ca = ((kc * 4 + quad) ^ (ar & 7)) * 8;
                const int cb = ((kc * 4 + quad) ^ (br & 7)) * 8;
                aF[i] = *(const bf16x8*)(As + ar * 64 + ca);
                bF[i] = *(const bf16x8*)(Bs + br * 64 + cb);
            }
            #pragma unroll
            for (int mi = 0; mi < 4; ++mi)
                #pragma unroll
                for (int ni = 0; ni < 4; ++ni)
                    acc[mi][ni] = __builtin_amdgcn_mfma_f32_16x16x32_bf16(
                        aF[mi], bF[ni], acc[mi][ni], 0, 0, 0);
        }
    }

    // Epilogue: es += exp2((v-1)*20*log2e); packed argmax; [row][32] partials.
    const float C20 = 28.853900817779268f;  // 20*log2(e)
    const int chunk = nTile * 2 + wvN;
    #pragma unroll
    for (int mi = 0; mi < 4; ++mi) {
        float    es[4] = {0.f, 0.f, 0.f, 0.f};
        unsigned km[4] = {0u, 0u, 0u, 0u};
        #pragma unroll
        for (int ni = 0; ni < 4; ++ni) {
            const int col = nTile * 128 + wvN * 64 + ni * 16 + l15;
            const unsigned colenc = 2047u - (unsigned)col;
            const bool valid = (col < NC);
            #pragma unroll
            for (int r = 0; r < 4; ++r) {
                float v = valid ? acc[mi][ni][r] : -3.0f;
                es[r] += exp2f((v - 1.0f) * C20);
                unsigned u = __float_as_uint(v);
                unsigned k = u ^ (unsigned)(((int)u >> 31) | 0x80000000);
                unsigned pk = (k & 0xFFFFF800u) | colenc;  // bigger v, then smaller col
                km[r] = pk > km[r] ? pk : km[r];
            }
        }
        #pragma unroll
        for (int r = 0; r < 4; ++r) {
            #pragma unroll
            for (int m = 1; m < 16; m <<= 1) {
                es[r] += __shfl_xor(es[r], m, 64);
                unsigned x = __shfl_xor(km[r], m, 64);
                km[r] = x > km[r] ? x : km[r];
            }
        }
        if (l15 == 0) {
            #pragma unroll
            for (int r = 0; r < 4; ++r) {
                const int row = mTile * 128 + wvM * 64 + mi * 16 + quad * 4 + r;
                es_p [(size_t)row * NCHUNK + chunk] = es[r];
                key_p[(size_t)row * NCHUNK + chunk] = km[r];
            }
        }
    }
}

// ---------------------------------------------------------------------------
// Kernel 3: gather + finalize, 8-lanes-per-dot version.
//   Wave handles 2 rows. Per row: lane = d*8+e; dot d (0=label, 1..5=aux)
//   loads 128 B of fn[row] and wn[col] -> 64 MACs -> 3-round group shfl.
//   6 broadcast shfls assemble tgt/auxsum; 5-round coalesced combine of the
//   [row][32] es/key partials. All lanes end with identical loss/acc.
//   14 serial shfl rounds total (was 41). Plain per-block partial stores.
// ---------------------------------------------------------------------------
__global__ __launch_bounds__(256) void gather_fin_kernel(
    const __bf16* __restrict__ fn, const __bf16* __restrict__ wn,
    const int* __restrict__ label, const int* __restrict__ aux,
    const float* __restrict__ es_p, const unsigned* __restrict__ key_p,
    float* __restrict__ blkpart)
{
    const int lane = threadIdx.x & 63;
    const int wv   = threadIdx.x >> 6;
    const int d    = lane >> 3;      // dot index (0..7; 6 used)
    const int e    = lane & 7;       // 128B segment within the row

    float lsum = 0.f, asum = 0.f;
    #pragma unroll
    for (int rr = 0; rr < 2; ++rr) {
        const int row = blockIdx.x * 8 + wv * 2 + rr;
        const int lab = label[row];

        float dv = 0.f;
        if (d < 6) {
            const int col = (d == 0) ? lab : aux[row * NAUX + (d - 1)];
            const bf16x8* fp = (const bf16x8*)(fn + (size_t)row * EMB) + e * 8;
            const bf16x8* wp = (const bf16x8*)(wn + (size_t)col * EMB) + e * 8;
            #pragma unroll
            for (int i = 0; i < 8; ++i) {
                bf16x8 a = fp[i], b = wp[i];
                #pragma unroll
                for (int jj = 0; jj < 8; ++jj) dv += (float)a[jj] * (float)b[jj];
            }
        }
        dv += __shfl_xor(dv, 1, 64);
        dv += __shfl_xor(dv, 2, 64);
        dv += __shfl_xor(dv, 4, 64);
        const float tgt  = __shfl(dv, 0, 64) * 20.0f;
        const float auxs = (__shfl(dv,  8, 64) + __shfl(dv, 16, 64) +
                            __shfl(dv, 24, 64) + __shfl(dv, 32, 64) +
                            __shfl(dv, 40, 64)) * 20.0f;

        const int c = lane & 31;
        float    es = es_p [(size_t)row * NCHUNK + c];
        unsigned k  = key_p[(size_t)row * NCHUNK + c];
        #pragma unroll
        for (int m = 1; m < 32; m <<= 1) {
            es += __shfl_xor(es, m, 64);
            unsigned x = __shfl_xor(k, m, 64);
            k = x > k ? x : k;
        }
        const int amax = 2047 - (int)(k & 0x7FFu);
        lsum += 20.0f + logf(es) - 0.95f * tgt - 0.01f * auxs;
        asum += (amax == lab) ? 1.0f : 0.0f;
    }

    __shared__ float sl[4], sa[4];
    if (lane == 0) { sl[wv] = lsum; sa[wv] = asum; }
    __syncthreads();
    if (threadIdx.x == 0) {
        blkpart[blockIdx.x]        = sl[0] + sl[1] + sl[2] + sl[3];
        blkpart[GBLK + blockIdx.x] = sa[0] + sa[1] + sa[2] + sa[3];
    }
}

// ---------------------------------------------------------------------------
// Kernel 4: reduce 2048 block partials -> (loss, acc). One block, independent
// unrolled loads.
// ---------------------------------------------------------------------------
__global__ __launch_bounds__(256) void fin2_kernel(
    const float* __restrict__ blkpart, float* __restrict__ out)
{
    float l = 0.f, a = 0.f;
    #pragma unroll
    for (int i = 0; i < GBLK / 256; ++i) {
        l += blkpart[i * 256 + threadIdx.x];
        a += blkpart[GBLK + i * 256 + threadIdx.x];
    }
    #pragma unroll
    for (int m = 1; m < 64; m <<= 1) {
        l += __shfl_xor(l, m, 64);
        a += __shfl_xor(a, m, 64);
    }
    __shared__ float sl[4], sa[4];
    const int wv = threadIdx.x >> 6;
    if ((threadIdx.x & 63) == 0) { sl[wv] = l; sa[wv] = a; }
    __syncthreads();
    if (threadIdx.x == 0) {
        out[0] = (sl[0] + sl[1] + sl[2] + sl[3]) / (float)BS;
        out[1] = (sa[0] + sa[1] + sa[2] + sa[3]) / (float)BS;
    }
}

// ---------------------------------------------------------------------------
// Workspace layout (bytes):
//   fn      @ 0         (16,777,216)  BS x 512 bf16
//   wn      @ 16777216  ( 2,097,152)  NCP(2048) x 512 bf16 (rows >=2000 zero)
//   es_p    @ 18874368  ( 2,097,152)  [BS][32] f32
//   key_p   @ 20971520  ( 2,097,152)  [BS][32] u32
//   blkpart @ 23068672  (    16,384)  [2][2048] f32
// ---------------------------------------------------------------------------
extern "C" void kernel_launch(void* const* d_in, const int* in_sizes, int n_in,
                              void* d_out, int out_size, void* d_ws, size_t ws_size,
                              hipStream_t stream)
{
    const float* feat  = (const float*)d_in[0];
    const float* wemb  = (const float*)d_in[1];
    const int*   label = (const int*)d_in[2];
    const int*   aux   = (const int*)d_in[3];

    char* ws = (char*)d_ws;
    __bf16*   fn      = (__bf16*)(ws);
    __bf16*   wn      = (__bf16*)(ws + 16777216);
    float*    es_p    = (float*)(ws + 18874368);
    unsigned* key_p   = (unsigned*)(ws + 20971520);
    float*    blkpart = (float*)(ws + 23068672);
    float*    out     = (float*)d_out;

    hipLaunchKernelGGL(norm_kernel, dim3((BS + NCP) / 16), dim3(256), 0, stream,
                       feat, wemb, fn, wn);
    hipLaunchKernelGGL(main_kernel, dim3((BS / 128) * (NCP / 128)), dim3(256), 0, stream,
                       fn, wn, es_p, key_p);
    hipLaunchKernelGGL(gather_fin_kernel, dim3(GBLK), dim3(256), 0, stream,
                       fn, wn, label, aux, es_p, key_p, blkpart);
    hipLaunchKernelGGL(fin2_kernel, dim3(1), dim3(256), 0, stream, blkpart, out);
}

// Round 12
// 148.684 us; speedup vs baseline: 1.2074x; 1.2074x over previous
//
#include <hip/hip_runtime.h>
#include <hip/hip_bf16.h>
#include <hip/hip_fp8.h>
#include <stdint.h>

#define BS   16384
#define NC   2000
#define NCP  2048            // padded N (wn zero-filled rows 2000..2047)
#define EMB  512
#define NAUX 5
#define NCHUNK 32            // partial chunks per row: nTile*2 + wvN
#define GBLK 4096            // gather_fin blocks (4 rows each)

typedef __bf16 bf16x8 __attribute__((ext_vector_type(8)));
typedef float  f32x4  __attribute__((ext_vector_type(4)));

// ---------------------------------------------------------------------------
// Kernel 1: row-normalize features and word_embed; write fp8 e4m3 (for the
// MFMA GEMM) AND bf16 (for gather_fin). Zero-fill pad rows. 16 lanes/row.
// ---------------------------------------------------------------------------
__global__ __launch_bounds__(256) void norm_kernel(
    const float* __restrict__ feat, const float* __restrict__ wemb,
    unsigned char* __restrict__ fn8, unsigned char* __restrict__ wn8,
    __bf16* __restrict__ fnb, __bf16* __restrict__ wnb)
{
    const int sub = threadIdx.x & 15;                    // lane-in-row
    const int row = blockIdx.x * 16 + (threadIdx.x >> 4);

    if (row >= BS + NC) {  // padding rows -> zeros (masked in epilogue)
        const int pr = row - BS;
        uint4 z4 = {0, 0, 0, 0};
        ((uint4*)(wn8 + (size_t)pr * EMB))[sub * 2]     = z4;
        ((uint4*)(wn8 + (size_t)pr * EMB))[sub * 2 + 1] = z4;
        bf16x8 z = {};
        bf16x8* d = (bf16x8*)(wnb + (size_t)pr * EMB) + sub * 4;
        #pragma unroll
        for (int i = 0; i < 4; ++i) d[i] = z;
        return;
    }
    const float* src;
    unsigned char* dst8;
    __bf16* dstb;
    if (row < BS) { src = feat + (size_t)row * EMB;
                    dst8 = fn8 + (size_t)row * EMB;        dstb = fnb + (size_t)row * EMB; }
    else          { src = wemb + (size_t)(row - BS) * EMB;
                    dst8 = wn8 + (size_t)(row - BS) * EMB; dstb = wnb + (size_t)(row - BS) * EMB; }

    const float4* s4 = (const float4*)src + sub * 8;     // 32 floats per lane
    float4 x[8];
    float ss = 0.f;
    #pragma unroll
    for (int i = 0; i < 8; ++i) {
        x[i] = s4[i];
        ss += x[i].x * x[i].x + x[i].y * x[i].y + x[i].z * x[i].z + x[i].w * x[i].w;
    }
    #pragma unroll
    for (int m = 1; m < 16; m <<= 1) ss += __shfl_xor(ss, m, 64);
    const float scale = 1.0f / fmaxf(sqrtf(ss), 1e-12f);

    float v[32];
    #pragma unroll
    for (int i = 0; i < 8; ++i) {
        v[4*i]   = x[i].x * scale; v[4*i+1] = x[i].y * scale;
        v[4*i+2] = x[i].z * scale; v[4*i+3] = x[i].w * scale;
    }
    // bf16 copy
    bf16x8* db = (bf16x8*)dstb + sub * 4;
    #pragma unroll
    for (int i = 0; i < 4; ++i) {
        bf16x8 o;
        #pragma unroll
        for (int jj = 0; jj < 8; ++jj) o[jj] = (__bf16)v[8*i + jj];
        db[i] = o;
    }
    // fp8 e4m3 (OCP) copy
    unsigned char pb[32];
    #pragma unroll
    for (int i = 0; i < 32; ++i)
        pb[i] = __hip_cvt_float_to_fp8(v[i], __HIP_SATFINITE, __HIP_E4M3);
    uint4* d8 = (uint4*)(dst8 + sub * 32);
    d8[0] = *(const uint4*)(pb);
    d8[1] = *(const uint4*)(pb + 16);
}

// ---------------------------------------------------------------------------
// Kernel 2: fp8 GEMM, BK=256 -> only TWO staging iterations (2 drains vs 8).
//   128x128 tile, 4 waves 2x2; A,B tiles 128x256 fp8 = 32 KB each (64 KB
//   total static LDS). Staging via global_load_lds width=16 + explicit
//   s_waitcnt(0). 16B-chunk XOR swizzle (chunk ^ (row&7)); frag reads are
//   ds_read_b64 at chunk (kc*2 + (quad>>1)) ^ (m&7), half = quad&1.
//   XCD swizzle: xcd=bid&7 owns 16 mTiles, mTile-major (keeps r7's FETCH win).
// mfma_f32_16x16x32_fp8_fp8 layouts (same geometry as verified bf16 16x16x32):
//   A frag: lane(m=lane&15, q=lane>>4) holds A[m][q*8+j], 8 fp8 = 8 B (long)
//   B frag: lane(n=lane&15, q)         holds B[q*8+j][n] = wn[n][q*8+j]
//   C/D:    col(n) = lane&15, row(m) = q*4 + reg   [dtype-independent]
// ---------------------------------------------------------------------------
__global__ __launch_bounds__(256) void main_kernel(
    const unsigned char* __restrict__ fn8, const unsigned char* __restrict__ wn8,
    float* __restrict__ es_p, unsigned* __restrict__ key_p)
{
    __shared__ __align__(16) unsigned char As[128 * 256];
    __shared__ __align__(16) unsigned char Bs[128 * 256];

    const int tid   = threadIdx.x;
    const int lane  = tid & 63;
    const int l15   = lane & 15;
    const int quad  = lane >> 4;
    const int wv    = tid >> 6;
    const int wvM   = wv >> 1;
    const int wvN   = wv & 1;
    const int xcd   = blockIdx.x & 7;
    const int j     = blockIdx.x >> 3;           // 0..255 within XCD
    const int mTile = xcd * 16 + (j >> 4);       // 0..127
    const int nTile = j & 15;                    // 0..15

    const unsigned char* fbase = fn8 + (size_t)mTile * 128 * EMB;
    const unsigned char* wbase = wn8 + (size_t)nTile * 128 * EMB;

    // Staging: each global_load_lds covers 4 rows x 256 B (64 lanes x 16 B).
    // Lane L: row_in_4 = L>>4, phys chunk = L&15, logical = phys ^ (row&7).
    const int rIn = lane >> 4;                    // 0..3
    const int cPh = lane & 15;                    // phys 16B chunk in row
    f32x4 acc[4][4] = {};

    #pragma unroll
    for (int kk = 0; kk < 2; ++kk) {
        __syncthreads();                          // previous iter's readers done
        #pragma unroll
        for (int p = 0; p < 8; ++p) {
            const int slot = wv * 8 + p;          // 0..31 -> rows slot*4..+4
            const int row  = slot * 4 + rIn;
            const int cLog = cPh ^ (row & 7);
            const size_t goff = (size_t)row * EMB + kk * 256 + cLog * 16;
            __builtin_amdgcn_global_load_lds(
                (const __attribute__((address_space(1))) void*)(fbase + goff),
                (__attribute__((address_space(3))) void*)(As + slot * 1024), 16, 0, 0);
            __builtin_amdgcn_global_load_lds(
                (const __attribute__((address_space(1))) void*)(wbase + goff),
                (__attribute__((address_space(3))) void*)(Bs + slot * 1024), 16, 0, 0);
        }
        __builtin_amdgcn_s_waitcnt(0);            // drain global->LDS DMA
        __syncthreads();                          // staged tile visible to all

        #pragma unroll
        for (int kc = 0; kc < 8; ++kc) {
            long aF[4], bF[4];
            const int c16  = kc * 2 + (quad >> 1);
            const int hoff = (quad & 1) << 3;
            #pragma unroll
            for (int i = 0; i < 4; ++i) {
                const int ar = wvM * 64 + i * 16 + l15;
                const int br = wvN * 64 + i * 16 + l15;
                const int ca = ((c16 ^ (l15 & 7)) << 4) + hoff;
                aF[i] = *(const long*)(As + ar * 256 + ca);
                bF[i] = *(const long*)(Bs + br * 256 + ca);
            }
            #pragma unroll
            for (int mi = 0; mi < 4; ++mi)
                #pragma unroll
                for (int ni = 0; ni < 4; ++ni)
                    acc[mi][ni] = __builtin_amdgcn_mfma_f32_16x16x32_fp8_fp8(
                        aF[mi], bF[ni], acc[mi][ni], 0, 0, 0);
        }
    }

    // Epilogue: es += exp2((v-1)*20*log2e); packed argmax; [row][32] partials.
    const float C20 = 28.853900817779268f;  // 20*log2(e)
    const int chunk = nTile * 2 + wvN;
    #pragma unroll
    for (int mi = 0; mi < 4; ++mi) {
        float    es[4] = {0.f, 0.f, 0.f, 0.f};
        unsigned km[4] = {0u, 0u, 0u, 0u};
        #pragma unroll
        for (int ni = 0; ni < 4; ++ni) {
            const int col = nTile * 128 + wvN * 64 + ni * 16 + l15;
            const unsigned colenc = 2047u - (unsigned)col;
            const bool valid = (col < NC);
            #pragma unroll
            for (int r = 0; r < 4; ++r) {
                float v = valid ? acc[mi][ni][r] : -3.0f;
                es[r] += exp2f((v - 1.0f) * C20);
                unsigned u = __float_as_uint(v);
                unsigned k = u ^ (unsigned)(((int)u >> 31) | 0x80000000);
                unsigned pk = (k & 0xFFFFF800u) | colenc;  // bigger v, then smaller col
                km[r] = pk > km[r] ? pk : km[r];
            }
        }
        #pragma unroll
        for (int r = 0; r < 4; ++r) {
            #pragma unroll
            for (int m = 1; m < 16; m <<= 1) {
                es[r] += __shfl_xor(es[r], m, 64);
                unsigned x = __shfl_xor(km[r], m, 64);
                km[r] = x > km[r] ? x : km[r];
            }
        }
        if (l15 == 0) {
            #pragma unroll
            for (int r = 0; r < 4; ++r) {
                const int row = mTile * 128 + wvM * 64 + mi * 16 + quad * 4 + r;
                es_p [(size_t)row * NCHUNK + chunk] = es[r];
                key_p[(size_t)row * NCHUNK + chunk] = km[r];
            }
        }
    }
}

// ---------------------------------------------------------------------------
// Kernel 3: gather + finalize (r10's proven version, reads bf16 copies).
// One wave per row: 6 dots, coalesced [row][32] combine, per-block partial.
// ---------------------------------------------------------------------------
__global__ __launch_bounds__(256) void gather_fin_kernel(
    const __bf16* __restrict__ fnb, const __bf16* __restrict__ wnb,
    const int* __restrict__ label, const int* __restrict__ aux,
    const float* __restrict__ es_p, const unsigned* __restrict__ key_p,
    float* __restrict__ blkpart)
{
    const int lane = threadIdx.x & 63;
    const int wv   = threadIdx.x >> 6;
    const int row  = blockIdx.x * 4 + wv;

    bf16x8 f8 = *((const bf16x8*)fnb + (size_t)row * (EMB / 8) + lane);
    float fv[8];
    #pragma unroll
    for (int j = 0; j < 8; ++j) fv[j] = (float)f8[j];

    const int lab = label[row];
    int cols[6];
    cols[0] = lab;
    #pragma unroll
    for (int j = 0; j < NAUX; ++j) cols[j + 1] = aux[row * NAUX + j];

    float res[6];
    #pragma unroll
    for (int c = 0; c < 6; ++c) {
        bf16x8 w8 = *((const bf16x8*)wnb + (size_t)cols[c] * (EMB / 8) + lane);
        float d = 0.f;
        #pragma unroll
        for (int j = 0; j < 8; ++j) d += fv[j] * (float)w8[j];
        #pragma unroll
        for (int m = 1; m < 64; m <<= 1) d += __shfl_xor(d, m, 64);
        res[c] = d;
    }
    const float tgt  = res[0] * 20.0f;
    const float auxs = (res[1] + res[2] + res[3] + res[4] + res[5]) * 20.0f;

    const int c = lane & 31;
    float    es = es_p [(size_t)row * NCHUNK + c];
    unsigned k  = key_p[(size_t)row * NCHUNK + c];
    #pragma unroll
    for (int m = 1; m < 32; m <<= 1) {
        es += __shfl_xor(es, m, 64);
        unsigned x = __shfl_xor(k, m, 64);
        k = x > k ? x : k;
    }
    const int amax = 2047 - (int)(k & 0x7FFu);
    const float loss = 20.0f + logf(es) - 0.95f * tgt - 0.01f * auxs;
    const float acc  = (amax == lab) ? 1.0f : 0.0f;

    __shared__ float sl[4], sa[4];
    if (lane == 0) { sl[wv] = loss; sa[wv] = acc; }
    __syncthreads();
    if (threadIdx.x == 0) {
        blkpart[blockIdx.x]        = sl[0] + sl[1] + sl[2] + sl[3];
        blkpart[GBLK + blockIdx.x] = sa[0] + sa[1] + sa[2] + sa[3];
    }
}

// ---------------------------------------------------------------------------
// Kernel 4: reduce 4096 block partials -> (loss, acc). One block.
// ---------------------------------------------------------------------------
__global__ __launch_bounds__(256) void fin2_kernel(
    const float* __restrict__ blkpart, float* __restrict__ out)
{
    float l = 0.f, a = 0.f;
    for (int i = threadIdx.x; i < GBLK; i += 256) {
        l += blkpart[i];
        a += blkpart[GBLK + i];
    }
    #pragma unroll
    for (int m = 1; m < 64; m <<= 1) {
        l += __shfl_xor(l, m, 64);
        a += __shfl_xor(a, m, 64);
    }
    __shared__ float sl[4], sa[4];
    const int wv = threadIdx.x >> 6;
    if ((threadIdx.x & 63) == 0) { sl[wv] = l; sa[wv] = a; }
    __syncthreads();
    if (threadIdx.x == 0) {
        out[0] = (sl[0] + sl[1] + sl[2] + sl[3]) / (float)BS;
        out[1] = (sa[0] + sa[1] + sa[2] + sa[3]) / (float)BS;
    }
}

// ---------------------------------------------------------------------------
// Workspace layout (bytes):
//   fn8     @ 0         ( 8,388,608)  BS x 512 fp8
//   wn8     @ 8388608   ( 1,048,576)  NCP x 512 fp8 (pad rows zero)
//   fnb     @ 9437184   (16,777,216)  BS x 512 bf16
//   wnb     @ 26214400  ( 2,097,152)  NCP x 512 bf16 (pad rows zero)
//   es_p    @ 28311552  ( 2,097,152)  [BS][32] f32
//   key_p   @ 30408704  ( 2,097,152)  [BS][32] u32
//   blkpart @ 32505856  (    32,768)  [2][4096] f32
// ---------------------------------------------------------------------------
extern "C" void kernel_launch(void* const* d_in, const int* in_sizes, int n_in,
                              void* d_out, int out_size, void* d_ws, size_t ws_size,
                              hipStream_t stream)
{
    const float* feat  = (const float*)d_in[0];
    const float* wemb  = (const float*)d_in[1];
    const int*   label = (const int*)d_in[2];
    const int*   aux   = (const int*)d_in[3];

    char* ws = (char*)d_ws;
    unsigned char* fn8     = (unsigned char*)(ws);
    unsigned char* wn8     = (unsigned char*)(ws + 8388608);
    __bf16*        fnb     = (__bf16*)(ws + 9437184);
    __bf16*        wnb     = (__bf16*)(ws + 26214400);
    float*         es_p    = (float*)(ws + 28311552);
    unsigned*      key_p   = (unsigned*)(ws + 30408704);
    float*         blkpart = (float*)(ws + 32505856);
    float*         out     = (float*)d_out;

    hipLaunchKernelGGL(norm_kernel, dim3((BS + NCP) / 16), dim3(256), 0, stream,
                       feat, wemb, fn8, wn8, fnb, wnb);
    hipLaunchKernelGGL(main_kernel, dim3((BS / 128) * (NCP / 128)), dim3(256), 0, stream,
                       fn8, wn8, es_p, key_p);
    hipLaunchKernelGGL(gather_fin_kernel, dim3(GBLK), dim3(256), 0, stream,
                       fnb, wnb, label, aux, es_p, key_p, blkpart);
    hipLaunchKernelGGL(fin2_kernel, dim3(1), dim3(256), 0, stream, blkpart, out);
}